// Round 2
// baseline (575.498 us; speedup 1.0000x reference)
//
#include <hip/hip_runtime.h>
#include <hip/hip_bf16.h>

#define Mm 8
#define Nn 512
#define NEe 409
#define NIi 103
#define Bb 512
#define Dd 243
#define Tt 16
#define SPROW 640      // spike row (bf16): e[0:409) pad[409:512) i[512:615) pad[615:640)
#define WCROW 1152     // packed weight row: inter(512) | E-rec(512) | I-rec(128)
#define DEC_I 0.33333334f  // (float)(1.0 - 1.0/1.5)

typedef __bf16 v8bf __attribute__((ext_vector_type(8)));
typedef float  v4f  __attribute__((ext_vector_type(4)));
typedef int    v4i  __attribute__((ext_vector_type(4)));

__device__ __forceinline__ float quantf(float w) {
    // fake_quant forward == clip(round-half-even(w), -8, 7)  (step = 1.0)
    float q = rintf(w);
    return fminf(fmaxf(q, -8.0f), 7.0f);
}

// ---------------- zero spike buffers (pads must be 0; ws is poisoned) ----------------
__global__ void k_zero(int4* __restrict__ p, int n) {
    int i = blockIdx.x * blockDim.x + threadIdx.x;
    if (i < n) p[i] = make_int4(0, 0, 0, 0);
}

// ---------------- pack quantized recurrent weights as bf16 (exact small ints) -------
// Wc[m][n][k]: k<512: W_inter[m-1][n][k] (roll); 512..1023: EE/EI; 1024..1151: IE/II
__global__ void k_pack(const float* __restrict__ Wint, const float* __restrict__ WEE,
                       const float* __restrict__ WEI, const float* __restrict__ WIE,
                       const float* __restrict__ WII, unsigned short* __restrict__ Wc) {
    int i = blockIdx.x * 256 + threadIdx.x;
    if (i >= Mm * Nn * WCROW) return;
    int k = i % WCROW;
    int n = (i / WCROW) & (Nn - 1);
    int m = i / (WCROW * Nn);
    float w = 0.0f;
    if (k < 512) {
        if (k < NEe) w = Wint[((((m + 7) & 7) * Nn) + n) * NEe + k];
    } else if (k < 1024) {
        int j = k - 512;
        if (j < NEe) w = (n < NEe) ? WEE[((m * NEe) + n) * NEe + j]
                                   : WEI[((m * NIi) + (n - NEe)) * NEe + j];
    } else {
        int j = k - 1024;
        if (j < NIi) w = (n < NEe) ? WIE[((m * NEe) + n) * NIi + j]
                                   : WII[((m * NIi) + (n - NEe)) * NIi + j];
    }
    __hip_bfloat16 hb = __float2bfloat16(quantf(w));  // exact: |int| <= 8
    Wc[i] = *reinterpret_cast<unsigned short*>(&hb);
}

// ---------------- ext_proj = x @ qW_in^T + b_in  (fp32, sequential over d) ----------
__global__ void k_ext(const float* __restrict__ x, const float* __restrict__ Win,
                      const float* __restrict__ bin, float* __restrict__ ext) {
    __shared__ float xs[64][68];
    __shared__ float wsm[64][68];
    const int bid = blockIdx.x;          // 512 blocks: m(8) x bt(8) x nt(8)
    const int m  = bid >> 6;
    const int bt = (bid >> 3) & 7;
    const int nt = bid & 7;
    const int b0 = bt * 64, n0 = nt * 64;
    const int t = threadIdx.x;
    const int tb4 = (t & 15) * 4;
    const int tn4 = (t >> 4) * 4;
    const int sr = t >> 2;
    const int sc = (t & 3) * 16;
    float c[4][4];
#pragma unroll
    for (int i = 0; i < 4; ++i)
#pragma unroll
        for (int j = 0; j < 4; ++j) c[i][j] = 0.0f;

    for (int d0 = 0; d0 < Dd; d0 += 64) {
#pragma unroll
        for (int j = 0; j < 16; ++j) {
            int d = d0 + sc + j;
            float xv = 0.0f, wv = 0.0f;
            if (d < Dd) {
                xv = x[(b0 + sr) * Dd + d];
                wv = quantf(Win[((m * Nn) + n0 + sr) * Dd + d]);
            }
            xs[sc + j][sr] = xv;
            wsm[sc + j][sr] = wv;
        }
        __syncthreads();
        const int dmax = min(64, Dd - d0);
        for (int d = 0; d < dmax; ++d) {
            float4 av = *(const float4*)&xs[d][tb4];
            float4 wv = *(const float4*)&wsm[d][tn4];
            float a[4] = {av.x, av.y, av.z, av.w};
            float wq[4] = {wv.x, wv.y, wv.z, wv.w};
#pragma unroll
            for (int i = 0; i < 4; ++i)
#pragma unroll
                for (int j = 0; j < 4; ++j)
                    c[i][j] = fmaf(a[i], wq[j], c[i][j]);
        }
        __syncthreads();
    }
#pragma unroll
    for (int i = 0; i < 4; ++i)
#pragma unroll
        for (int j = 0; j < 4; ++j) {
            float val = __fadd_rn(c[i][j], bin[m * Nn + n0 + tn4 + j]);
            ext[(size_t)(m * Bb + b0 + tb4 + i) * Nn + n0 + tn4 + j] = val;
        }
}

// ---------------- one LIF tick: bf16 MFMA GEMM + exact-order LIF update -------------
// 256 WGs x 256 thr; WG = (mesh m=wg&7, b-tile 64, n-tile 128); K=1152 in 9 chunks of 128.
__global__ void __launch_bounds__(256, 1)
k_tick(const unsigned short* __restrict__ Wc,
       const unsigned short* __restrict__ SR,
       unsigned short* __restrict__ SW,
       const float* __restrict__ ext,
       float* __restrict__ vG,
       float* __restrict__ out,
       int t) {
    __shared__ __align__(16) unsigned short sA[2][64][136];   // 128 + 8 pad
    __shared__ __align__(16) unsigned short sB[2][128][136];

    const int wg = blockIdx.x;
    const int m  = wg & 7;
    const int bt = (wg >> 3) & 7;
    const int nt = wg >> 6;              // 0..3
    const int b0 = bt * 64;
    const int n0 = nt * 128;
    const int pm = (m + 7) & 7;

    const int tid  = threadIdx.x;
    const int w    = tid >> 6;
    const int lane = tid & 63;
    const int bh   = w & 1;              // 32-row half of b-tile
    const int nh   = w >> 1;             // 64-col half of n-tile
    const int quad = lane >> 4;
    const int li   = lane & 15;

    // staging coords: A 4 chunks/thread, B 8 chunks/thread (16B = 8 bf16 each)
    int rowA[4], colA[4], rowB[8], colB[8];
#pragma unroll
    for (int j = 0; j < 4; ++j) { int ch = tid + j * 256; rowA[j] = ch >> 4; colA[j] = (ch & 15) * 8; }
#pragma unroll
    for (int j = 0; j < 8; ++j) { int ch = tid + j * 256; rowB[j] = ch >> 4; colB[j] = (ch & 15) * 8; }

    float decs[4]; int offs[4]; int nels[4];
#pragma unroll
    for (int tn = 0; tn < 4; ++tn) {
        int n = n0 + nh * 64 + tn * 16 + li;
        nels[tn] = n;
        decs[tn] = (n < NEe) ? 0.5f : DEC_I;
        offs[tn] = (n < NEe) ? n : (n + 103);   // i-region of spike row starts at 512
    }
    const int bbase = b0 + bh * 32;

    const unsigned short* AbasePrev = SR + (size_t)(pm * Bb + b0) * SPROW;
    const unsigned short* AbaseOwn  = SR + (size_t)(m  * Bb + b0) * SPROW;
    const unsigned short* WcBase    = Wc + (size_t)(m * Nn + n0) * WCROW;

    v4f acc[2][4];
#pragma unroll
    for (int tb = 0; tb < 2; ++tb)
#pragma unroll
        for (int tn = 0; tn < 4; ++tn) acc[tb][tn] = (v4f){0.f, 0.f, 0.f, 0.f};
    float c[2][4][4];

    // stage chunk 0 (k0=0 -> prev-mesh e segment)
    {
#pragma unroll
        for (int j = 0; j < 4; ++j)
            *(v4i*)&sA[0][rowA[j]][colA[j]] = *(const v4i*)(AbasePrev + (size_t)rowA[j] * SPROW + colA[j]);
#pragma unroll
        for (int j = 0; j < 8; ++j)
            *(v4i*)&sB[0][rowB[j]][colB[j]] = *(const v4i*)(WcBase + (size_t)rowB[j] * WCROW + colB[j]);
    }
    __syncthreads();

    for (int it = 0; it < 9; ++it) {
        const int buf = it & 1;
        v4i nA[4], nB[8];
        if (it < 8) {
            const int k0 = (it + 1) * 128;
            const unsigned short* ab; int ko;
            if (k0 < 512) { ab = AbasePrev; ko = k0; }
            else          { ab = AbaseOwn;  ko = k0 - 512; }
#pragma unroll
            for (int j = 0; j < 4; ++j)
                nA[j] = *(const v4i*)(ab + (size_t)rowA[j] * SPROW + ko + colA[j]);
#pragma unroll
            for (int j = 0; j < 8; ++j)
                nB[j] = *(const v4i*)(WcBase + (size_t)rowB[j] * WCROW + k0 + colB[j]);
        }
        // compute current chunk: 4 k-steps of 32
#pragma unroll
        for (int ks = 0; ks < 128; ks += 32) {
            v8bf a0 = *(const v8bf*)&sA[buf][bh * 32 + li][ks + quad * 8];
            v8bf a1 = *(const v8bf*)&sA[buf][bh * 32 + 16 + li][ks + quad * 8];
#pragma unroll
            for (int tn = 0; tn < 4; ++tn) {
                v8bf bfr = *(const v8bf*)&sB[buf][nh * 64 + tn * 16 + li][ks + quad * 8];
                acc[0][tn] = __builtin_amdgcn_mfma_f32_16x16x32_bf16(a0, bfr, acc[0][tn], 0, 0, 0);
                acc[1][tn] = __builtin_amdgcn_mfma_f32_16x16x32_bf16(a1, bfr, acc[1][tn], 0, 0, 0);
            }
        }
        if (it < 8) {
            const int nb = buf ^ 1;
#pragma unroll
            for (int j = 0; j < 4; ++j) *(v4i*)&sA[nb][rowA[j]][colA[j]] = nA[j];
#pragma unroll
            for (int j = 0; j < 8; ++j) *(v4i*)&sB[nb][rowB[j]][colB[j]] = nB[j];
        }
        __syncthreads();
        // segment flushes preserve the reference's exact fp32 add order:
        // c = ((ext_proj+inter) + Erec) + Irec; each partial is an exact integer.
        if (it == 3) {
#pragma unroll
            for (int tb = 0; tb < 2; ++tb)
#pragma unroll
                for (int tn = 0; tn < 4; ++tn) {
#pragma unroll
                    for (int r = 0; r < 4; ++r) {
                        int b = bbase + tb * 16 + quad * 4 + r;
                        float e = ext[(size_t)(m * Bb + b) * Nn + nels[tn]];
                        c[tb][tn][r] = __fadd_rn(e, acc[tb][tn][r]);
                    }
                    acc[tb][tn] = (v4f){0.f, 0.f, 0.f, 0.f};
                }
        } else if (it == 7 || it == 8) {
#pragma unroll
            for (int tb = 0; tb < 2; ++tb)
#pragma unroll
                for (int tn = 0; tn < 4; ++tn) {
#pragma unroll
                    for (int r = 0; r < 4; ++r)
                        c[tb][tn][r] = __fadd_rn(c[tb][tn][r], acc[tb][tn][r]);
                    acc[tb][tn] = (v4f){0.f, 0.f, 0.f, 0.f};
                }
        }
    }

    // LIF update, exact np op order: v' = (v*decay) + c; spike iff v' >= 1.0
#pragma unroll
    for (int tb = 0; tb < 2; ++tb)
#pragma unroll
        for (int tn = 0; tn < 4; ++tn)
#pragma unroll
            for (int r = 0; r < 4; ++r) {
                int b = bbase + tb * 16 + quad * 4 + r;
                size_t vidx = (size_t)(m * Bb + b) * Nn + nels[tn];
                float v = (t == 0) ? 0.0f : vG[vidx];
                float vn = __fadd_rn(__fmul_rn(v, decs[tn]), c[tb][tn][r]);
                int s = (vn >= 1.0f) ? 1 : 0;
                vG[vidx] = s ? 0.0f : vn;
                SW[(size_t)(m * Bb + b) * SPROW + offs[tn]] = s ? 0x3F80u : 0u;
                float* op = &out[(size_t)b * (Mm * Nn) + m * Nn + nels[tn]];
                if (t == 0) *op = (float)s;
                else        *op = *op + (float)s;
            }
}

extern "C" void kernel_launch(void* const* d_in, const int* in_sizes, int n_in,
                              void* d_out, int out_size, void* d_ws, size_t ws_size,
                              hipStream_t stream) {
    const float* x    = (const float*)d_in[0];
    const float* Win  = (const float*)d_in[1];
    const float* bin  = (const float*)d_in[2];
    const float* Wint = (const float*)d_in[3];
    const float* WEE  = (const float*)d_in[4];
    const float* WEI  = (const float*)d_in[5];
    const float* WIE  = (const float*)d_in[6];
    const float* WII  = (const float*)d_in[7];
    float* out = (float*)d_out;

    char* ws = (char*)d_ws;
    unsigned short* Wc  = (unsigned short*)ws;                 // 8*512*1152*2 = 9,437,184
    unsigned short* Sp0 = (unsigned short*)(ws + 9437184);     // 8*512*640*2  = 5,242,880
    unsigned short* Sp1 = (unsigned short*)(ws + 9437184 + 5242880);
    float* extw = (float*)(ws + 9437184 + 2 * 5242880);        // 8*512*512*4 = 8,388,608
    float* vG   = (float*)(ws + 9437184 + 2 * 5242880 + 8388608);

    int n16 = (2 * 5242880) / 16;
    k_zero<<<(n16 + 255) / 256, 256, 0, stream>>>((int4*)Sp0, n16);
    k_pack<<<(Mm * Nn * WCROW + 255) / 256, 256, 0, stream>>>(Wint, WEE, WEI, WIE, WII, Wc);
    k_ext<<<512, 256, 0, stream>>>(x, Win, bin, extw);

    for (int t = 0; t < Tt; ++t) {
        unsigned short* SR = (t & 1) ? Sp1 : Sp0;
        unsigned short* SW = (t & 1) ? Sp0 : Sp1;
        k_tick<<<256, 256, 0, stream>>>(Wc, SR, SW, (const float*)extw, vG, out, t);
    }
}

// Round 4
// 442.610 us; speedup vs baseline: 1.3002x; 1.3002x over previous
//
#include <hip/hip_runtime.h>
#include <hip/hip_bf16.h>

#define Mm 8
#define Nn 512
#define NEe 409
#define NIi 103
#define Bb 512
#define Dd 243
#define Tt 16
#define SPROW 640      // spike row (bf16): e[0:409) pad[409:512) i[512:615) pad[615:640)
#define WCROW 1152     // packed weight row: inter(512) | E-rec(512) | I-rec(128)
#define DEC_I 0.33333334f  // (float)(1.0 - 1.0/1.5)

typedef __bf16 v8bf __attribute__((ext_vector_type(8)));
typedef float  v4f  __attribute__((ext_vector_type(4)));
typedef int    v4i  __attribute__((ext_vector_type(4)));

__device__ __forceinline__ float quantf(float w) {
    // fake_quant forward == clip(round-half-even(w), -8, 7)  (step = 1.0)
    float q = rintf(w);
    return fminf(fmaxf(q, -8.0f), 7.0f);
}

// ---------------- zero spike buffers (pads must be 0; ws is poisoned) ----------------
__global__ void k_zero(int4* __restrict__ p, int n) {
    int i = blockIdx.x * blockDim.x + threadIdx.x;
    if (i < n) p[i] = make_int4(0, 0, 0, 0);
}

// ---------------- pack quantized recurrent weights as bf16 (exact small ints) -------
// Wc[m][n][k]: k<512: W_inter[m-1][n][k] (roll); 512..1023: EE/EI; 1024..1151: IE/II
__global__ void k_pack(const float* __restrict__ Wint, const float* __restrict__ WEE,
                       const float* __restrict__ WEI, const float* __restrict__ WIE,
                       const float* __restrict__ WII, unsigned short* __restrict__ Wc) {
    int i = blockIdx.x * 256 + threadIdx.x;
    if (i >= Mm * Nn * WCROW) return;
    int k = i % WCROW;
    int n = (i / WCROW) & (Nn - 1);
    int m = i / (WCROW * Nn);
    float w = 0.0f;
    if (k < 512) {
        if (k < NEe) w = Wint[((((m + 7) & 7) * Nn) + n) * NEe + k];
    } else if (k < 1024) {
        int j = k - 512;
        if (j < NEe) w = (n < NEe) ? WEE[((m * NEe) + n) * NEe + j]
                                   : WEI[((m * NIi) + (n - NEe)) * NEe + j];
    } else {
        int j = k - 1024;
        if (j < NIi) w = (n < NEe) ? WIE[((m * NEe) + n) * NIi + j]
                                   : WII[((m * NIi) + (n - NEe)) * NIi + j];
    }
    __hip_bfloat16 hb = __float2bfloat16(quantf(w));  // exact: |int| <= 8
    Wc[i] = *reinterpret_cast<unsigned short*>(&hb);
}

// ---------------- ext_proj = x @ qW_in^T + b_in  (fp32, sequential over d) ----------
__global__ void k_ext(const float* __restrict__ x, const float* __restrict__ Win,
                      const float* __restrict__ bin, float* __restrict__ ext) {
    __shared__ float xs[64][68];
    __shared__ float wsm[64][68];
    const int bid = blockIdx.x;          // 512 blocks: m(8) x bt(8) x nt(8)
    const int m  = bid >> 6;
    const int bt = (bid >> 3) & 7;
    const int nt = bid & 7;
    const int b0 = bt * 64, n0 = nt * 64;
    const int t = threadIdx.x;
    const int tb4 = (t & 15) * 4;
    const int tn4 = (t >> 4) * 4;
    const int sr = t >> 2;
    const int sc = (t & 3) * 16;
    float c[4][4];
#pragma unroll
    for (int i = 0; i < 4; ++i)
#pragma unroll
        for (int j = 0; j < 4; ++j) c[i][j] = 0.0f;

    for (int d0 = 0; d0 < Dd; d0 += 64) {
#pragma unroll
        for (int j = 0; j < 16; ++j) {
            int d = d0 + sc + j;
            float xv = 0.0f, wv = 0.0f;
            if (d < Dd) {
                xv = x[(b0 + sr) * Dd + d];
                wv = quantf(Win[((m * Nn) + n0 + sr) * Dd + d]);
            }
            xs[sc + j][sr] = xv;
            wsm[sc + j][sr] = wv;
        }
        __syncthreads();
        const int dmax = min(64, Dd - d0);
        for (int d = 0; d < dmax; ++d) {
            float4 av = *(const float4*)&xs[d][tb4];
            float4 wv = *(const float4*)&wsm[d][tn4];
            float a[4] = {av.x, av.y, av.z, av.w};
            float wq[4] = {wv.x, wv.y, wv.z, wv.w};
#pragma unroll
            for (int i = 0; i < 4; ++i)
#pragma unroll
                for (int j = 0; j < 4; ++j)
                    c[i][j] = fmaf(a[i], wq[j], c[i][j]);
        }
        __syncthreads();
    }
#pragma unroll
    for (int i = 0; i < 4; ++i)
#pragma unroll
        for (int j = 0; j < 4; ++j) {
            float val = __fadd_rn(c[i][j], bin[m * Nn + n0 + tn4 + j]);
            ext[(size_t)(m * Bb + b0 + tb4 + i) * Nn + n0 + tn4 + j] = val;
        }
}

// ---------------- one LIF tick: bf16 MFMA GEMM + exact-order LIF update -------------
// 256 WGs x 512 thr (8 waves -> 2 waves/SIMD for latency hiding).
// WG = (mesh m=wg&7, b-tile 64, n-tile 128); wave tile 32x32 (acc 2x2).
// K=1152 in 9 double-buffered chunks of 128. Fragment indexing identical to the
// verified round-2 kernel (bf16 16x16x32: A[m=li][k=quad*8+j], C col=li,row=quad*4+r).
__global__ void __launch_bounds__(512, 2)
k_tick(const unsigned short* __restrict__ Wc,
       const unsigned short* __restrict__ SR,
       unsigned short* __restrict__ SW,
       const float* __restrict__ ext,
       float* __restrict__ vG,
       unsigned char* __restrict__ cntG,
       float* __restrict__ out,
       int t) {
    __shared__ __align__(16) unsigned short sA[2][64][136];   // 128 + 8 pad
    __shared__ __align__(16) unsigned short sB[2][128][136];

    const int wg = blockIdx.x;
    const int m  = wg & 7;               // mesh -> XCD affinity heuristic
    const int bt = (wg >> 3) & 7;
    const int nt = wg >> 6;              // 0..3
    const int b0 = bt * 64;
    const int n0 = nt * 128;
    const int pm = (m + 7) & 7;

    const int tid  = threadIdx.x;
    const int w    = tid >> 6;           // 0..7
    const int lane = tid & 63;
    const int bh   = w & 1;              // 32-row half of b-tile
    const int nh   = w >> 1;             // 0..3: 32-col slice of n-tile
    const int quad = lane >> 4;
    const int li   = lane & 15;

    // staging coords: A 2 chunks/thread, B 4 chunks/thread (16B = 8 bf16 each)
    int rowA[2], colA[2], rowB[4], colB[4];
#pragma unroll
    for (int j = 0; j < 2; ++j) { int ch = tid + j * 512; rowA[j] = ch >> 4; colA[j] = (ch & 15) * 8; }
#pragma unroll
    for (int j = 0; j < 4; ++j) { int ch = tid + j * 512; rowB[j] = ch >> 4; colB[j] = (ch & 15) * 8; }

    float decs[2]; int offs[2]; int nels[2];
#pragma unroll
    for (int tn = 0; tn < 2; ++tn) {
        int n = n0 + nh * 32 + tn * 16 + li;
        nels[tn] = n;
        decs[tn] = (n < NEe) ? 0.5f : DEC_I;
        offs[tn] = (n < NEe) ? n : (n + 103);   // i-region of spike row starts at 512
    }
    const int bbase = b0 + bh * 32;

    const unsigned short* AbasePrev = SR + (size_t)(pm * Bb + b0) * SPROW;
    const unsigned short* AbaseOwn  = SR + (size_t)(m  * Bb + b0) * SPROW;
    const unsigned short* WcBase    = Wc + (size_t)(m * Nn + n0) * WCROW;

    v4f acc[2][2];
#pragma unroll
    for (int tb = 0; tb < 2; ++tb)
#pragma unroll
        for (int tn = 0; tn < 2; ++tn) acc[tb][tn] = (v4f){0.f, 0.f, 0.f, 0.f};
    float c[2][2][4];

    // stage chunk 0 (k0=0 -> prev-mesh e segment)
#pragma unroll
    for (int j = 0; j < 2; ++j)
        *(v4i*)&sA[0][rowA[j]][colA[j]] = *(const v4i*)(AbasePrev + (size_t)rowA[j] * SPROW + colA[j]);
#pragma unroll
    for (int j = 0; j < 4; ++j)
        *(v4i*)&sB[0][rowB[j]][colB[j]] = *(const v4i*)(WcBase + (size_t)rowB[j] * WCROW + colB[j]);
    __syncthreads();

    for (int it = 0; it < 9; ++it) {
        const int buf = it & 1;
        v4i nA[2], nB[4];
        if (it < 8) {
            const int k0 = (it + 1) * 128;
            const unsigned short* ab; int ko;
            if (k0 < 512) { ab = AbasePrev; ko = k0; }
            else          { ab = AbaseOwn;  ko = k0 - 512; }
#pragma unroll
            for (int j = 0; j < 2; ++j)
                nA[j] = *(const v4i*)(ab + (size_t)rowA[j] * SPROW + ko + colA[j]);
#pragma unroll
            for (int j = 0; j < 4; ++j)
                nB[j] = *(const v4i*)(WcBase + (size_t)rowB[j] * WCROW + k0 + colB[j]);
        }
        // compute current chunk: 4 k-steps of 32
#pragma unroll
        for (int ks = 0; ks < 128; ks += 32) {
            v8bf a0 = *(const v8bf*)&sA[buf][bh * 32 + li][ks + quad * 8];
            v8bf a1 = *(const v8bf*)&sA[buf][bh * 32 + 16 + li][ks + quad * 8];
#pragma unroll
            for (int tn = 0; tn < 2; ++tn) {
                v8bf bfr = *(const v8bf*)&sB[buf][nh * 32 + tn * 16 + li][ks + quad * 8];
                acc[0][tn] = __builtin_amdgcn_mfma_f32_16x16x32_bf16(a0, bfr, acc[0][tn], 0, 0, 0);
                acc[1][tn] = __builtin_amdgcn_mfma_f32_16x16x32_bf16(a1, bfr, acc[1][tn], 0, 0, 0);
            }
        }
        if (it < 8) {
            const int nb = buf ^ 1;
#pragma unroll
            for (int j = 0; j < 2; ++j) *(v4i*)&sA[nb][rowA[j]][colA[j]] = nA[j];
#pragma unroll
            for (int j = 0; j < 4; ++j) *(v4i*)&sB[nb][rowB[j]][colB[j]] = nB[j];
        }
        __syncthreads();
        // segment flushes preserve the reference's exact fp32 add order:
        // c = ((ext_proj+inter) + Erec) + Irec; each partial is an exact integer.
        if (it == 3) {
#pragma unroll
            for (int tb = 0; tb < 2; ++tb)
#pragma unroll
                for (int tn = 0; tn < 2; ++tn) {
#pragma unroll
                    for (int r = 0; r < 4; ++r) {
                        int b = bbase + tb * 16 + quad * 4 + r;
                        float e = ext[(size_t)(m * Bb + b) * Nn + nels[tn]];
                        c[tb][tn][r] = __fadd_rn(e, acc[tb][tn][r]);
                    }
                    acc[tb][tn] = (v4f){0.f, 0.f, 0.f, 0.f};
                }
        } else if (it == 7 || it == 8) {
#pragma unroll
            for (int tb = 0; tb < 2; ++tb)
#pragma unroll
                for (int tn = 0; tn < 2; ++tn) {
#pragma unroll
                    for (int r = 0; r < 4; ++r)
                        c[tb][tn][r] = __fadd_rn(c[tb][tn][r], acc[tb][tn][r]);
                    acc[tb][tn] = (v4f){0.f, 0.f, 0.f, 0.f};
                }
        }
    }

    // LIF update, exact np op order: v' = (v*decay) + c; spike iff v' >= 1.0
    // State across launches: vG (fp32), cntG (u8). out written once at t==15.
#pragma unroll
    for (int tb = 0; tb < 2; ++tb)
#pragma unroll
        for (int tn = 0; tn < 2; ++tn)
#pragma unroll
            for (int r = 0; r < 4; ++r) {
                int b = bbase + tb * 16 + quad * 4 + r;
                size_t vidx = (size_t)(m * Bb + b) * Nn + nels[tn];
                float v = (t == 0) ? 0.0f : vG[vidx];
                float vn = __fadd_rn(__fmul_rn(v, decs[tn]), c[tb][tn][r]);
                int s = (vn >= 1.0f) ? 1 : 0;
                vG[vidx] = s ? 0.0f : vn;
                int nc = ((t == 0) ? 0 : (int)cntG[vidx]) + s;
                if (t == Tt - 1) {
                    out[(size_t)b * (Mm * Nn) + m * Nn + nels[tn]] = (float)nc;
                } else {
                    cntG[vidx] = (unsigned char)nc;
                    SW[(size_t)(m * Bb + b) * SPROW + offs[tn]] = s ? 0x3F80u : 0u;
                }
            }
}

extern "C" void kernel_launch(void* const* d_in, const int* in_sizes, int n_in,
                              void* d_out, int out_size, void* d_ws, size_t ws_size,
                              hipStream_t stream) {
    const float* x    = (const float*)d_in[0];
    const float* Win  = (const float*)d_in[1];
    const float* bin  = (const float*)d_in[2];
    const float* Wint = (const float*)d_in[3];
    const float* WEE  = (const float*)d_in[4];
    const float* WEI  = (const float*)d_in[5];
    const float* WIE  = (const float*)d_in[6];
    const float* WII  = (const float*)d_in[7];
    float* out = (float*)d_out;

    char* ws = (char*)d_ws;
    unsigned short* Wc  = (unsigned short*)ws;                 // 8*512*1152*2 = 9,437,184
    unsigned short* Sp0 = (unsigned short*)(ws + 9437184);     // 8*512*640*2  = 5,242,880
    unsigned short* Sp1 = (unsigned short*)(ws + 9437184 + 5242880);
    float* extw = (float*)(ws + 9437184 + 2 * 5242880);        // 8*512*512*4 = 8,388,608
    float* vG   = (float*)(ws + 9437184 + 2 * 5242880 + 8388608);        // 8,388,608
    unsigned char* cntG = (unsigned char*)(ws + 9437184 + 2 * 5242880 + 2 * 8388608); // 2 MB

    int n16 = (2 * 5242880) / 16;
    k_zero<<<(n16 + 255) / 256, 256, 0, stream>>>((int4*)Sp0, n16);
    k_pack<<<(Mm * Nn * WCROW + 255) / 256, 256, 0, stream>>>(Wint, WEE, WEI, WIE, WII, Wc);
    k_ext<<<512, 256, 0, stream>>>(x, Win, bin, extw);

    for (int t = 0; t < Tt; ++t) {
        unsigned short* SR = (t & 1) ? Sp1 : Sp0;
        unsigned short* SW = (t & 1) ? Sp0 : Sp1;
        k_tick<<<256, 512, 0, stream>>>(Wc, SR, SW, (const float*)extw, vG, cntG, out, t);
    }
}

// Round 5
// 342.714 us; speedup vs baseline: 1.6792x; 1.2915x over previous
//
#include <hip/hip_runtime.h>
#include <hip/hip_bf16.h>

#define Mm 8
#define Nn 512
#define NEe 409
#define NIi 103
#define Bb 512
#define Dd 243
#define Tt 16
#define SPROW 640      // spike row bytes (i8): e[0:409) pad[409:512) i[512:615) pad[615:640)
#define WCROW 1152     // packed weight row bytes (i8): inter(512) | E-rec(512) | I-rec(128)
#define DEC_I 0.33333334f  // (float)(1.0 - 1.0/1.5)

typedef int v4i __attribute__((ext_vector_type(4)));

__device__ __forceinline__ float quantf(float w) {
    // fake_quant forward == clip(round-half-even(w), -8, 7)  (step = 1.0)
    float q = rintf(w);
    return fminf(fmaxf(q, -8.0f), 7.0f);
}

// ---------------- zero spike buffers (pads must be 0; ws is poisoned) ----------------
__global__ void k_zero(int4* __restrict__ p, int n) {
    int i = blockIdx.x * blockDim.x + threadIdx.x;
    if (i < n) p[i] = make_int4(0, 0, 0, 0);
}

// ---------------- pack quantized recurrent weights as i8 (exact small ints) ---------
// Wc[m][n][k]: k<512: W_inter[m-1][n][k] (roll); 512..1023: EE/EI; 1024..1151: IE/II
__global__ void k_pack(const float* __restrict__ Wint, const float* __restrict__ WEE,
                       const float* __restrict__ WEI, const float* __restrict__ WIE,
                       const float* __restrict__ WII, signed char* __restrict__ Wc) {
    int i = blockIdx.x * 256 + threadIdx.x;
    if (i >= Mm * Nn * WCROW) return;
    int k = i % WCROW;
    int n = (i / WCROW) & (Nn - 1);
    int m = i / (WCROW * Nn);
    float w = 0.0f;
    if (k < 512) {
        if (k < NEe) w = Wint[((((m + 7) & 7) * Nn) + n) * NEe + k];
    } else if (k < 1024) {
        int j = k - 512;
        if (j < NEe) w = (n < NEe) ? WEE[((m * NEe) + n) * NEe + j]
                                   : WEI[((m * NIi) + (n - NEe)) * NEe + j];
    } else {
        int j = k - 1024;
        if (j < NIi) w = (n < NEe) ? WIE[((m * NEe) + n) * NIi + j]
                                   : WII[((m * NIi) + (n - NEe)) * NIi + j];
    }
    Wc[i] = (signed char)(int)quantf(w);
}

// ---------------- ext_proj = x @ qW_in^T + b_in  (fp32, sequential over d) ----------
__global__ void k_ext(const float* __restrict__ x, const float* __restrict__ Win,
                      const float* __restrict__ bin, float* __restrict__ ext) {
    __shared__ float xs[64][68];
    __shared__ float wsm[64][68];
    const int bid = blockIdx.x;          // 512 blocks: m(8) x bt(8) x nt(8)
    const int m  = bid >> 6;
    const int bt = (bid >> 3) & 7;
    const int nt = bid & 7;
    const int b0 = bt * 64, n0 = nt * 64;
    const int t = threadIdx.x;
    const int tb4 = (t & 15) * 4;
    const int tn4 = (t >> 4) * 4;
    const int sr = t >> 2;
    const int sc = (t & 3) * 16;
    float c[4][4];
#pragma unroll
    for (int i = 0; i < 4; ++i)
#pragma unroll
        for (int j = 0; j < 4; ++j) c[i][j] = 0.0f;

    for (int d0 = 0; d0 < Dd; d0 += 64) {
#pragma unroll
        for (int j = 0; j < 16; ++j) {
            int d = d0 + sc + j;
            float xv = 0.0f, wv = 0.0f;
            if (d < Dd) {
                xv = x[(b0 + sr) * Dd + d];
                wv = quantf(Win[((m * Nn) + n0 + sr) * Dd + d]);
            }
            xs[sc + j][sr] = xv;
            wsm[sc + j][sr] = wv;
        }
        __syncthreads();
        const int dmax = min(64, Dd - d0);
        for (int d = 0; d < dmax; ++d) {
            float4 av = *(const float4*)&xs[d][tb4];
            float4 wv = *(const float4*)&wsm[d][tn4];
            float a[4] = {av.x, av.y, av.z, av.w};
            float wq[4] = {wv.x, wv.y, wv.z, wv.w};
#pragma unroll
            for (int i = 0; i < 4; ++i)
#pragma unroll
                for (int j = 0; j < 4; ++j)
                    c[i][j] = fmaf(a[i], wq[j], c[i][j]);
        }
        __syncthreads();
    }
#pragma unroll
    for (int i = 0; i < 4; ++i)
#pragma unroll
        for (int j = 0; j < 4; ++j) {
            float val = __fadd_rn(c[i][j], bin[m * Nn + n0 + tn4 + j]);
            ext[(size_t)(m * Bb + b0 + tb4 + i) * Nn + n0 + tn4 + j] = val;
        }
}

// ---------------- one LIF tick: i8 MFMA GEMM + exact-order LIF update ---------------
// 512 WGs x 256 thr (4 waves); 2 blocks/CU (36.9 KB LDS, launch_bounds(256,4)) so
// barrier drains overlap across blocks. WG = (m=wg&7 [XCD L2 affinity], b-tile 64,
// n-tile 64); wave tile 32x32 (acc 2x2). K=1152 in 9 double-buffered chunks of 128 B.
// i8 16x16x64 fragment bet: A[row=lane&15][k=quad*16+j], B[col=lane&15][k=quad*16+j],
// C/D col=lane&15,row=quad*4+r (uniform gfx950 pattern, scaled from verified bf16).
__global__ void __launch_bounds__(256, 4)
k_tick(const signed char* __restrict__ Wc,
       const signed char* __restrict__ SR,
       signed char* __restrict__ SW,
       const float* __restrict__ ext,
       float* __restrict__ vG,
       unsigned char* __restrict__ cntG,
       float* __restrict__ out,
       int t) {
    __shared__ __align__(16) signed char sA[2][64][144];   // 128 + 16 pad
    __shared__ __align__(16) signed char sB[2][64][144];

    const int wg = blockIdx.x;           // 512: m(8) x bt(8) x nt(8)
    const int m  = wg & 7;               // mesh -> XCD affinity heuristic
    const int bt = (wg >> 3) & 7;
    const int nt = wg >> 6;              // 0..7
    const int b0 = bt * 64;
    const int n0 = nt * 64;
    const int pm = (m + 7) & 7;

    const int tid  = threadIdx.x;
    const int w    = tid >> 6;           // 0..3
    const int lane = tid & 63;
    const int bh   = w & 1;              // 32-row half of b-tile
    const int nh   = w >> 1;             // 32-col half of n-tile
    const int quad = lane >> 4;
    const int li   = lane & 15;

    // staging coords: 2 chunks/thread for each of A and B (16 B each; 64 rows x 8 chunks)
    int rowS[2], colS[2];
#pragma unroll
    for (int j = 0; j < 2; ++j) { int ch = tid + j * 256; rowS[j] = ch >> 3; colS[j] = (ch & 7) * 16; }

    float decs[2]; int offs[2]; int nels[2];
#pragma unroll
    for (int tn = 0; tn < 2; ++tn) {
        int n = n0 + nh * 32 + tn * 16 + li;
        nels[tn] = n;
        decs[tn] = (n < NEe) ? 0.5f : DEC_I;
        offs[tn] = (n < NEe) ? n : (n + 103);   // i-region of spike row starts at 512
    }
    const int bbase = b0 + bh * 32;

    const signed char* AbasePrev = SR + (size_t)(pm * Bb + b0) * SPROW;
    const signed char* AbaseOwn  = SR + (size_t)(m  * Bb + b0) * SPROW;
    const signed char* WcBase    = Wc + (size_t)(m * Nn + n0) * WCROW;

    v4i acc[2][2];
#pragma unroll
    for (int tb = 0; tb < 2; ++tb)
#pragma unroll
        for (int tn = 0; tn < 2; ++tn) acc[tb][tn] = (v4i){0, 0, 0, 0};
    float c[2][2][4];

    // stage chunk 0 (k0=0 -> prev-mesh e segment)
#pragma unroll
    for (int j = 0; j < 2; ++j) {
        *(v4i*)&sA[0][rowS[j]][colS[j]] = *(const v4i*)(AbasePrev + (size_t)rowS[j] * SPROW + colS[j]);
        *(v4i*)&sB[0][rowS[j]][colS[j]] = *(const v4i*)(WcBase + (size_t)rowS[j] * WCROW + colS[j]);
    }
    __syncthreads();

    for (int it = 0; it < 9; ++it) {
        const int buf = it & 1;
        v4i nA[2], nB[2];
        if (it < 8) {
            const int k0 = (it + 1) * 128;
            const signed char* ab; int ko;
            if (k0 < 512) { ab = AbasePrev; ko = k0; }
            else          { ab = AbaseOwn;  ko = k0 - 512; }   // k0=1024 -> ko=512 (i-region)
#pragma unroll
            for (int j = 0; j < 2; ++j) {
                nA[j] = *(const v4i*)(ab + (size_t)rowS[j] * SPROW + ko + colS[j]);
                nB[j] = *(const v4i*)(WcBase + (size_t)rowS[j] * WCROW + k0 + colS[j]);
            }
        }
        // compute current chunk: 2 k-steps of 64
#pragma unroll
        for (int ks = 0; ks < 128; ks += 64) {
            v4i af0 = *(const v4i*)&sA[buf][bh * 32 + li][ks + quad * 16];
            v4i af1 = *(const v4i*)&sA[buf][bh * 32 + 16 + li][ks + quad * 16];
#pragma unroll
            for (int tn = 0; tn < 2; ++tn) {
                v4i bfr = *(const v4i*)&sB[buf][nh * 32 + tn * 16 + li][ks + quad * 16];
                acc[0][tn] = __builtin_amdgcn_mfma_i32_16x16x64_i8(af0, bfr, acc[0][tn], 0, 0, 0);
                acc[1][tn] = __builtin_amdgcn_mfma_i32_16x16x64_i8(af1, bfr, acc[1][tn], 0, 0, 0);
            }
        }
        if (it < 8) {
            const int nb = buf ^ 1;
#pragma unroll
            for (int j = 0; j < 2; ++j) {
                *(v4i*)&sA[nb][rowS[j]][colS[j]] = nA[j];
                *(v4i*)&sB[nb][rowS[j]][colS[j]] = nB[j];
            }
        }
        __syncthreads();
        // segment flushes preserve the reference's exact fp32 add order:
        // c = ((ext_proj+inter) + Erec) + Irec; each partial is an exact integer.
        if (it == 3) {
#pragma unroll
            for (int tb = 0; tb < 2; ++tb)
#pragma unroll
                for (int tn = 0; tn < 2; ++tn) {
#pragma unroll
                    for (int r = 0; r < 4; ++r) {
                        int b = bbase + tb * 16 + quad * 4 + r;
                        float e = ext[(size_t)(m * Bb + b) * Nn + nels[tn]];
                        c[tb][tn][r] = __fadd_rn(e, (float)acc[tb][tn][r]);
                    }
                    acc[tb][tn] = (v4i){0, 0, 0, 0};
                }
        } else if (it == 7 || it == 8) {
#pragma unroll
            for (int tb = 0; tb < 2; ++tb)
#pragma unroll
                for (int tn = 0; tn < 2; ++tn) {
#pragma unroll
                    for (int r = 0; r < 4; ++r)
                        c[tb][tn][r] = __fadd_rn(c[tb][tn][r], (float)acc[tb][tn][r]);
                    acc[tb][tn] = (v4i){0, 0, 0, 0};
                }
        }
    }

    // LIF update, exact np op order: v' = (v*decay) + c; spike iff v' >= 1.0
    // State across launches: vG (fp32), cntG (u8). out written once at t==15.
#pragma unroll
    for (int tb = 0; tb < 2; ++tb)
#pragma unroll
        for (int tn = 0; tn < 2; ++tn)
#pragma unroll
            for (int r = 0; r < 4; ++r) {
                int b = bbase + tb * 16 + quad * 4 + r;
                size_t vidx = (size_t)(m * Bb + b) * Nn + nels[tn];
                float v = (t == 0) ? 0.0f : vG[vidx];
                float vn = __fadd_rn(__fmul_rn(v, decs[tn]), c[tb][tn][r]);
                int s = (vn >= 1.0f) ? 1 : 0;
                vG[vidx] = s ? 0.0f : vn;
                int nc = ((t == 0) ? 0 : (int)cntG[vidx]) + s;
                if (t == Tt - 1) {
                    out[(size_t)b * (Mm * Nn) + m * Nn + nels[tn]] = (float)nc;
                } else {
                    cntG[vidx] = (unsigned char)nc;
                    SW[(size_t)(m * Bb + b) * SPROW + offs[tn]] = (signed char)s;
                }
            }
}

extern "C" void kernel_launch(void* const* d_in, const int* in_sizes, int n_in,
                              void* d_out, int out_size, void* d_ws, size_t ws_size,
                              hipStream_t stream) {
    const float* x    = (const float*)d_in[0];
    const float* Win  = (const float*)d_in[1];
    const float* bin  = (const float*)d_in[2];
    const float* Wint = (const float*)d_in[3];
    const float* WEE  = (const float*)d_in[4];
    const float* WEI  = (const float*)d_in[5];
    const float* WIE  = (const float*)d_in[6];
    const float* WII  = (const float*)d_in[7];
    float* out = (float*)d_out;

    char* ws = (char*)d_ws;
    signed char* Wc  = (signed char*)ws;                       // 8*512*1152 = 4,718,592
    signed char* Sp0 = (signed char*)(ws + 4718592);           // 8*512*640  = 2,621,440
    signed char* Sp1 = Sp0 + 2621440;
    float* extw = (float*)(ws + 4718592 + 2 * 2621440);        // 8*512*512*4 = 8,388,608
    float* vG   = (float*)(ws + 4718592 + 2 * 2621440 + 8388608);            // 8,388,608
    unsigned char* cntG = (unsigned char*)(ws + 4718592 + 2 * 2621440 + 2 * 8388608); // 2 MB

    int n16 = (2 * 2621440) / 16;
    k_zero<<<(n16 + 255) / 256, 256, 0, stream>>>((int4*)Sp0, n16);
    k_pack<<<(Mm * Nn * WCROW + 255) / 256, 256, 0, stream>>>(Wint, WEE, WEI, WIE, WII, Wc);
    k_ext<<<512, 256, 0, stream>>>(x, Win, bin, extw);

    for (int t = 0; t < Tt; ++t) {
        signed char* SR = (t & 1) ? Sp1 : Sp0;
        signed char* SW = (t & 1) ? Sp0 : Sp1;
        k_tick<<<512, 256, 0, stream>>>(Wc, SR, SW, (const float*)extw, vG, cntG, out, t);
    }
}